// Round 1
// baseline (1421.148 us; speedup 1.0000x reference)
//
#include <hip/hip_runtime.h>

#ifndef __has_builtin
#define __has_builtin(x) 0
#endif

// ---- fast HW transcendentals (v_exp_f32 computes 2^x; v_rcp_f32) ----
__device__ __forceinline__ float fast_exp2(float x) {
#if __has_builtin(__builtin_amdgcn_exp2f)
  return __builtin_amdgcn_exp2f(x);
#else
  return exp2f(x);
#endif
}
__device__ __forceinline__ float fast_rcp(float x) {
#if __has_builtin(__builtin_amdgcn_rcpf)
  return __builtin_amdgcn_rcpf(x);
#else
  return 1.0f / x;
#endif
}

namespace {
constexpr int kB = 131072;
constexpr int kSeq = 150;
constexpr int kD = 2;
constexpr int kH = 64;
constexpr int kPred = 150;
constexpr int kSteps = kPred - 1;            // 149
constexpr float kDt = 150.0f / 149.0f;       // linspace(0,150,150) spacing
constexpr float kC = 2.8853900817779268f;    // 2*log2(e)
}  // namespace

// f(y) = tanh(y@W1+b1)@W2 + b2, folded:
//   tanh(q) = 1 - 2*rcp(1 + exp2(q*2log2e))
//   sw[j] = {W1[0][j]*C, W1[1][j]*C, -2*W2[j][0], -2*W2[j][1]}
//   sb[j] = b1[j]*C ;  base_d = b2[d] + sum_j W2[j][d]
__device__ __forceinline__ void feval(float y0, float y1,
                                      const float4* __restrict__ sw,
                                      const float4* __restrict__ sb4,
                                      float base0, float base1,
                                      float& f0, float& f1) {
  float a0 = 0.0f, a1 = 0.0f, c0 = 0.0f, c1 = 0.0f;  // dual accumulators (ILP)
#pragma unroll 4
  for (int q = 0; q < kH / 4; ++q) {
    float4 bb = sb4[q];
    float4 w0 = sw[4 * q + 0];
    float p0 = fmaf(y0, w0.x, fmaf(y1, w0.y, bb.x));
    float r0 = fast_rcp(1.0f + fast_exp2(p0));
    a0 = fmaf(r0, w0.z, a0);
    a1 = fmaf(r0, w0.w, a1);
    float4 w1 = sw[4 * q + 1];
    float p1 = fmaf(y0, w1.x, fmaf(y1, w1.y, bb.y));
    float r1 = fast_rcp(1.0f + fast_exp2(p1));
    c0 = fmaf(r1, w1.z, c0);
    c1 = fmaf(r1, w1.w, c1);
    float4 w2 = sw[4 * q + 2];
    float p2 = fmaf(y0, w2.x, fmaf(y1, w2.y, bb.z));
    float r2 = fast_rcp(1.0f + fast_exp2(p2));
    a0 = fmaf(r2, w2.z, a0);
    a1 = fmaf(r2, w2.w, a1);
    float4 w3 = sw[4 * q + 3];
    float p3 = fmaf(y0, w3.x, fmaf(y1, w3.y, bb.w));
    float r3 = fast_rcp(1.0f + fast_exp2(p3));
    c0 = fmaf(r3, w3.z, c0);
    c1 = fmaf(r3, w3.w, c1);
  }
  f0 = base0 + a0 + c0;
  f1 = base1 + a1 + c1;
}

__global__ __launch_bounds__(256, 2) void ode_kernel(
    const float* __restrict__ x, const float* __restrict__ W1,
    const float* __restrict__ b1, const float* __restrict__ W2,
    const float* __restrict__ b2, float* __restrict__ out) {
  __shared__ float4 sw[kH];
  __shared__ float4 sb4[kH / 4];
  __shared__ float sbase[2];

  const int t = threadIdx.x;
  if (t < kH) {
    // W1 is (D,H) row-major: W1[d][j] = W1[d*64+j]; W2 is (H,D): W2[j][d] = W2[j*2+d]
    sw[t] = make_float4(W1[t] * kC, W1[kH + t] * kC,
                        -2.0f * W2[2 * t], -2.0f * W2[2 * t + 1]);
    reinterpret_cast<float*>(sb4)[t] = b1[t] * kC;
  }
  if (t < 2) {
    float s = b2[t];
    for (int j = 0; j < kH; ++j) s += W2[2 * j + t];
    sbase[t] = s;
  }
  __syncthreads();
  const float base0 = sbase[0], base1 = sbase[1];

  const long bidx = (long)blockIdx.x * blockDim.x + t;
  const float* xp = x + bidx * (long)(kSeq * kD) + (kSeq - 1) * kD;
  float y0 = xp[0];
  float y1 = xp[1];
  float* op = out + bidx * (long)(kPred * kD);

  // previous even-index state (for paired float4 stores)
  float py0 = y0, py1 = y1;
  constexpr float DT = kDt, DT3 = kDt / 3.0f, DT8 = kDt / 8.0f;

  for (int s = 1; s <= kSteps; ++s) {
    float k1x, k1y, k2x, k2y, k3x, k3y, k4x, k4y;
    feval(y0, y1, sw, sb4, base0, base1, k1x, k1y);
    feval(fmaf(DT3, k1x, y0), fmaf(DT3, k1y, y1), sw, sb4, base0, base1, k2x, k2y);
    feval(fmaf(DT, k2x, fmaf(-DT3, k1x, y0)),
          fmaf(DT, k2y, fmaf(-DT3, k1y, y1)), sw, sb4, base0, base1, k3x, k3y);
    feval(fmaf(DT, k1x - k2x + k3x, y0),
          fmaf(DT, k1y - k2y + k3y, y1), sw, sb4, base0, base1, k4x, k4y);
    y0 = fmaf(DT8, k1x + 3.0f * (k2x + k3x) + k4x, y0);
    y1 = fmaf(DT8, k1y + 3.0f * (k2y + k3y) + k4y, y1);

    if (s & 1) {
      // write times (s-1, s) as one 16B store; offsets are 16B-aligned
      float4 v = make_float4(py0, py1, y0, y1);
      *reinterpret_cast<float4*>(op + (long)(s - 1) * 2) = v;
    } else {
      py0 = y0;
      py1 = y1;
    }
  }
}

extern "C" void kernel_launch(void* const* d_in, const int* in_sizes, int n_in,
                              void* d_out, int out_size, void* d_ws,
                              size_t ws_size, hipStream_t stream) {
  const float* x = (const float*)d_in[0];
  const float* W1 = (const float*)d_in[1];
  const float* b1 = (const float*)d_in[2];
  const float* W2 = (const float*)d_in[3];
  const float* b2 = (const float*)d_in[4];
  float* out = (float*)d_out;

  dim3 grid(kB / 256);
  dim3 block(256);
  hipLaunchKernelGGL(ode_kernel, grid, block, 0, stream, x, W1, b1, W2, b2,
                     out);
}